// Round 1
// baseline (2716.233 us; speedup 1.0000x reference)
//
#include <hip/hip_runtime.h>
#include <math.h>

// EELP: 20-step GNN scan.
// Restructure: per-pair fc1 -> per-node T/D precompute; fused node GEMM
// H @ [Omega_as | W_s*dinv | W_fc1_top | W_fc1_bot] (64x384); CSR aggregation;
// pair kernel does softmax gate + r accumulation; final r@Wp1@Wp2.

__device__ __forceinline__ float softplusf(float x) {
  return x > 20.f ? x : log1pf(expf(x));
}

// ---------------- setup kernels ----------------

__global__ void count_kernel(const int* __restrict__ col, int E, int* __restrict__ cnt) {
  int e = blockIdx.x * blockDim.x + threadIdx.x;
  if (e < E) atomicAdd(&cnt[col[e]], 1);
}

__global__ __launch_bounds__(1024) void scan_kernel(int* cnt, int* colptr, float* dinv, int N) {
  __shared__ int sums[1024];
  int tid = threadIdx.x;
  int chunk = (N + 1023) >> 10;
  int start = tid * chunk;
  int end = min(start + chunk, N);
  int s = 0;
  for (int i = start; i < end; i++) s += cnt[i];
  sums[tid] = s;
  __syncthreads();
  for (int off = 1; off < 1024; off <<= 1) {
    int v = (tid >= off) ? sums[tid - off] : 0;
    __syncthreads();
    sums[tid] += v;
    __syncthreads();
  }
  int incl = sums[tid];
  int run = incl - s;  // exclusive prefix
  for (int i = start; i < end; i++) {
    int c = cnt[i];
    colptr[i] = run;
    run += c;
    dinv[i] = rsqrtf((float)(c + 1));  // self-loop => deg = cnt+1 >= 1
    cnt[i] = 0;                        // reset for cursor reuse
  }
  if (tid == 1023) colptr[N] = incl;
}

__global__ void fill_kernel(const int* __restrict__ row, const int* __restrict__ col, int E,
                            const int* __restrict__ colptr, int* __restrict__ cur,
                            int* __restrict__ csr) {
  int e = blockIdx.x * blockDim.x + threadIdx.x;
  if (e < E) {
    int c = col[e];
    int pos = colptr[c] + atomicAdd(&cur[c], 1);
    csr[pos] = row[e];
  }
}

// Wnode (64 x 384): [Omega_as | W_s | W_fc1_top | W_fc1_bot]
__global__ void prep_weights(const float* __restrict__ Om, const float* __restrict__ Wsr,
                             const float* __restrict__ Wfc1, float* __restrict__ Wnode) {
  int idx = blockIdx.x * blockDim.x + threadIdx.x;
  if (idx >= 64 * 384) return;
  int k = idx / 384, j = idx % 384;
  float v;
  if (j < 64) {
    v = Om[k * 64 + j] - Om[j * 64 + k];
  } else if (j < 128) {
    int jj = j - 64;
    v = 0.5f * (Wsr[k * 64 + jj] + Wsr[jj * 64 + k]);
  } else if (j < 256) {
    int jj = j - 128;
    v = Wfc1[k * 128 + jj];
  } else {
    int jj = j - 256;
    v = Wfc1[(64 + k) * 128 + jj];
  }
  Wnode[idx] = v;
}

// ---------------- generic skinny GEMM: (nrows x K) @ (K x M), 64-wide col tiles ----------------
// block = 128 threads, tile = 32 rows x 64 cols; SCALE: multiply col tile [64,128) by dinv[row]

template <int K, bool RELU, bool SCALE>
__global__ __launch_bounds__(128) void gemm_nk(const float* __restrict__ X, int xld,
                                               const float* __restrict__ W, int wld,
                                               float* __restrict__ Y, int yld, int nrows,
                                               const float* __restrict__ dinv) {
  __shared__ float Xs[32 * (K + 4)];
  __shared__ float Ws[K * 64];
  const int tid = threadIdx.x;
  const int row0 = blockIdx.x * 32;
  const int col0 = blockIdx.y * 64;

  for (int i = tid; i < 32 * (K / 4); i += 128) {
    int rr = i / (K / 4), kk = (i % (K / 4)) * 4;
    int gr = row0 + rr;
    float4 v = make_float4(0.f, 0.f, 0.f, 0.f);
    if (gr < nrows) v = *(const float4*)(X + (size_t)gr * xld + kk);
    *(float4*)(Xs + rr * (K + 4) + kk) = v;
  }
  for (int i = tid; i < K * 16; i += 128) {
    int kk = i >> 4, cc = (i & 15) * 4;
    *(float4*)(Ws + kk * 64 + cc) = *(const float4*)(W + (size_t)kk * wld + col0 + cc);
  }
  __syncthreads();

  const int tn = tid >> 4;        // 8 groups x 4 rows
  const int tc = (tid & 15) * 4;  // 16 groups x 4 cols
  float acc[4][4] = {};
  for (int k = 0; k < K; k += 4) {
    float4 xv[4];
#pragma unroll
    for (int i = 0; i < 4; i++) xv[i] = *(float4*)(Xs + (tn * 4 + i) * (K + 4) + k);
#pragma unroll
    for (int kk = 0; kk < 4; kk++) {
      float4 wv = *(float4*)(Ws + (k + kk) * 64 + tc);
#pragma unroll
      for (int i = 0; i < 4; i++) {
        float xs = (&xv[i].x)[kk];
        acc[i][0] = fmaf(xs, wv.x, acc[i][0]);
        acc[i][1] = fmaf(xs, wv.y, acc[i][1]);
        acc[i][2] = fmaf(xs, wv.z, acc[i][2]);
        acc[i][3] = fmaf(xs, wv.w, acc[i][3]);
      }
    }
  }
#pragma unroll
  for (int i = 0; i < 4; i++) {
    int gr = row0 + tn * 4 + i;
    if (gr >= nrows) continue;
    float sc = 1.0f;
    if (SCALE && col0 == 64) sc = dinv[gr];
    float4 o;
    o.x = acc[i][0] * sc;
    o.y = acc[i][1] * sc;
    o.z = acc[i][2] * sc;
    o.w = acc[i][3] * sc;
    if (RELU) {
      o.x = fmaxf(o.x, 0.f);
      o.y = fmaxf(o.y, 0.f);
      o.z = fmaxf(o.z, 0.f);
      o.w = fmaxf(o.w, 0.f);
    }
    *(float4*)(Y + (size_t)gr * yld + col0 + tc) = o;
  }
}

// ---------------- aggregation: wave per node ----------------
// sym = dinv[c]*(sum_in Bs[s] + Bs[c]); dH = relu(tanh(sym - relu(A)));
// H += dH; ft/fb = old_H . Wfv halves (cross-lane reduce)

__global__ __launch_bounds__(256) void aggregate_kernel(
    const float* __restrict__ NodeBuf, const float* __restrict__ dinv,
    const int* __restrict__ colptr, const int* __restrict__ csr, const float* __restrict__ Wfv,
    float* __restrict__ H, float* __restrict__ dH, float* __restrict__ ftfb, int N) {
  int c = blockIdx.x * 4 + (threadIdx.x >> 6);
  int j = threadIdx.x & 63;
  if (c >= N) return;
  const float* Bs = NodeBuf + 64;
  float acc = Bs[(size_t)c * 384 + j];  // self-loop term (Bs already scaled by dinv[src])
  int beg = colptr[c], end = colptr[c + 1];
  for (int i = beg; i < end; i++) {
    int s = csr[i];
    acc += Bs[(size_t)s * 384 + j];
  }
  float sym = dinv[c] * acc;
  float a = NodeBuf[(size_t)c * 384 + j];
  float dh = tanhf(sym - fmaxf(a, 0.f));
  dh = fmaxf(dh, 0.f);
  dH[(size_t)c * 64 + j] = dh;
  float h = H[(size_t)c * 64 + j];
  H[(size_t)c * 64 + j] = h + dh;
  float p0 = h * Wfv[j];
  float p1 = h * Wfv[64 + j];
#pragma unroll
  for (int off = 32; off >= 1; off >>= 1) {
    p0 += __shfl_xor(p0, off, 64);
    p1 += __shfl_xor(p1, off, 64);
  }
  if (j == 0) {
    ftfb[2 * c] = p0;
    ftfb[2 * c + 1] = p1;
  }
}

// ---------------- r init: r = concat(H0[src], H0[dst]) ----------------

__global__ void rinit_kernel(const float* __restrict__ H, const int* __restrict__ pairs,
                             float* __restrict__ r, int P) {
  int idx = blockIdx.x * blockDim.x + threadIdx.x;
  int p = idx >> 5;
  if (p >= P) return;
  int q = idx & 31;
  int j = q * 4;
  int node = (j < 64) ? pairs[2 * p] : pairs[2 * p + 1];
  int jj = j & 63;
  float4 v = *(const float4*)(H + (size_t)node * 64 + jj);
  *(float4*)(r + (size_t)p * 128 + j) = v;
}

// ---------------- pair kernel: 16 lanes per pair ----------------

__global__ __launch_bounds__(256) void pair_kernel(
    const float* __restrict__ NodeBuf, const float* __restrict__ ftfb,
    const float* __restrict__ dH, const int* __restrict__ pairs, const float* __restrict__ gum,
    const float* __restrict__ Wfc2, float* __restrict__ r, float* __restrict__ ts, int P,
    int first) {
  int p = blockIdx.x * 16 + (threadIdx.x >> 4);
  int l = threadIdx.x & 15;
  if (p >= P) return;
  int src = pairs[2 * p], dst = pairs[2 * p + 1];
  const float* Tn = NodeBuf + (size_t)src * 384 + 128;
  const float* Dn = NodeBuf + (size_t)dst * 384 + 256;
  float4 t0 = *(const float4*)(Tn + l * 8);
  float4 t1 = *(const float4*)(Tn + l * 8 + 4);
  float4 d0 = *(const float4*)(Dn + l * 8);
  float4 d1 = *(const float4*)(Dn + l * 8 + 4);
  float z[8];
  z[0] = t0.x + d0.x; z[1] = t0.y + d0.y; z[2] = t0.z + d0.z; z[3] = t0.w + d0.w;
  z[4] = t1.x + d1.x; z[5] = t1.y + d1.y; z[6] = t1.z + d1.z; z[7] = t1.w + d1.w;
  float l0 = 0.f, l1 = 0.f;
#pragma unroll
  for (int i = 0; i < 8; i++) {
    float zz = fmaxf(z[i], 0.f);
    int m = l * 8 + i;
    l0 = fmaf(zz, Wfc2[2 * m], l0);
    l1 = fmaf(zz, Wfc2[2 * m + 1], l1);
  }
#pragma unroll
  for (int off = 1; off < 16; off <<= 1) {
    l0 += __shfl_xor(l0, off, 64);
    l1 += __shfl_xor(l1, off, 64);
  }
  float nu = softplusf(ftfb[2 * src] + ftfb[2 * dst + 1]) + 1.0f;
  float g0 = gum[2 * (size_t)p], g1 = gum[2 * (size_t)p + 1];
  float dlt = ((l1 + g1) - (l0 + g0)) / nu;
  float tau = 1.0f / (1.0f + expf(dlt));

  const float* drp = (l < 8) ? (dH + (size_t)src * 64 + l * 8) : (dH + (size_t)dst * 64 + (l - 8) * 8);
  float4 a0 = *(const float4*)drp;
  float4 a1 = *(const float4*)(drp + 4);
  float* rp = r + (size_t)p * 128 + l * 8;
  float4 r0 = *(float4*)rp;
  float4 r1 = *(float4*)(rp + 4);
  r0.x = fmaf(tau, a0.x, r0.x); r0.y = fmaf(tau, a0.y, r0.y);
  r0.z = fmaf(tau, a0.z, r0.z); r0.w = fmaf(tau, a0.w, r0.w);
  r1.x = fmaf(tau, a1.x, r1.x); r1.y = fmaf(tau, a1.y, r1.y);
  r1.z = fmaf(tau, a1.z, r1.z); r1.w = fmaf(tau, a1.w, r1.w);
  *(float4*)rp = r0;
  *(float4*)(rp + 4) = r1;
  if (l == 0) {
    if (first) ts[p] = tau;
    else ts[p] += tau;
  }
}

// ---------------- final score: mid = relu(r@Wp1) via gemm, then dot with Wp2 ----------------

__global__ void score_kernel(const float* __restrict__ mid, const float* __restrict__ Wp2,
                             float* __restrict__ out, int P) {
  int p = blockIdx.x * 16 + (threadIdx.x >> 4);
  int l = threadIdx.x & 15;
  if (p >= P) return;
  const float* mp = mid + (size_t)p * 64 + l * 4;
  float4 m = *(const float4*)mp;
  float s = m.x * Wp2[l * 4] + m.y * Wp2[l * 4 + 1] + m.z * Wp2[l * 4 + 2] + m.w * Wp2[l * 4 + 3];
#pragma unroll
  for (int off = 1; off < 16; off <<= 1) s += __shfl_xor(s, off, 64);
  if (l == 0) out[p] = s;
}

// ---------------- launch ----------------

extern "C" void kernel_launch(void* const* d_in, const int* in_sizes, int n_in, void* d_out,
                              int out_size, void* d_ws, size_t ws_size, hipStream_t stream) {
  const float* x = (const float*)d_in[0];
  const int* edge = (const int*)d_in[1];
  const int* pairs = (const int*)d_in[2];
  const float* gumbel = (const float*)d_in[3];
  const float* Wenc = (const float*)d_in[4];
  const float* Om = (const float*)d_in[5];
  const float* Wsr = (const float*)d_in[6];
  const float* Wfc1 = (const float*)d_in[7];
  const float* Wfc2 = (const float*)d_in[8];
  const float* Wfv = (const float*)d_in[9];
  const float* Wp1 = (const float*)d_in[10];
  const float* Wp2 = (const float*)d_in[11];
  const int IN = 128;
  const int N = in_sizes[0] / IN;
  const int E = in_sizes[1] / 2;
  const int P = in_sizes[2] / 2;
  const int L = in_sizes[3] / (2 * P);
  float* out = (float*)d_out;

  char* wsb = (char*)d_ws;
  size_t off = 0;
  auto alloc = [&](size_t bytes) -> char* {
    char* p = wsb + off;
    off = (off + bytes + 255) & ~(size_t)255;
    return p;
  };
  float* dinv = (float*)alloc((size_t)N * 4);
  int* cnt = (int*)alloc((size_t)N * 4);
  int* colptr = (int*)alloc((size_t)(N + 1) * 4);
  int* csr = (int*)alloc((size_t)E * 4);
  float* Wnode = (float*)alloc((size_t)64 * 384 * 4);
  float* H = (float*)alloc((size_t)N * 64 * 4);
  float* dHb = (float*)alloc((size_t)N * 64 * 4);
  float* NodeBuf = (float*)alloc((size_t)N * 384 * 4);
  float* ftfb = (float*)alloc((size_t)N * 2 * 4);
  float* r = (float*)alloc((size_t)P * 128 * 4);
  float* mid = (float*)alloc((size_t)P * 64 * 4);
  (void)ws_size;
  (void)n_in;
  (void)out_size;

  const int* erow = edge;
  const int* ecol = edge + E;

  hipMemsetAsync(cnt, 0, (size_t)N * 4, stream);
  count_kernel<<<(E + 255) / 256, 256, 0, stream>>>(ecol, E, cnt);
  scan_kernel<<<1, 1024, 0, stream>>>(cnt, colptr, dinv, N);
  fill_kernel<<<(E + 255) / 256, 256, 0, stream>>>(erow, ecol, E, colptr, cnt, csr);
  prep_weights<<<(64 * 384 + 255) / 256, 256, 0, stream>>>(Om, Wsr, Wfc1, Wnode);

  dim3 ge((N + 31) / 32, 1);
  gemm_nk<128, true, false><<<ge, 128, 0, stream>>>(x, IN, Wenc, 64, H, 64, N, nullptr);
  rinit_kernel<<<((P * 32) + 255) / 256, 256, 0, stream>>>(H, pairs, r, P);

  dim3 gn((N + 31) / 32, 6);
  for (int t = 0; t < L; t++) {
    gemm_nk<64, false, true><<<gn, 128, 0, stream>>>(H, 64, Wnode, 384, NodeBuf, 384, N, dinv);
    aggregate_kernel<<<(N + 3) / 4, 256, 0, stream>>>(NodeBuf, dinv, colptr, csr, Wfv, H, dHb,
                                                      ftfb, N);
    pair_kernel<<<(P + 15) / 16, 256, 0, stream>>>(NodeBuf, ftfb, dHb, pairs,
                                                   gumbel + (size_t)t * P * 2, Wfc2, r, out + P,
                                                   P, t == 0);
  }
  dim3 gm((P + 31) / 32, 1);
  gemm_nk<128, true, false><<<gm, 128, 0, stream>>>(r, 128, Wp1, 64, mid, 64, P, nullptr);
  score_kernel<<<(P + 15) / 16, 256, 0, stream>>>(mid, Wp2, out, P);
}

// Round 2
// 1541.010 us; speedup vs baseline: 1.7626x; 1.7626x over previous
//
#include <hip/hip_runtime.h>
#include <math.h>

// EELP: 20-step GNN scan, MFMA-bf16 edition.
// All GEMMs via mfma_f32_16x16x32_bf16, no LDS (weights pre-transposed [col][k],
// L1/L2-resident). NodeBuf/dH/H-copy kept in bf16 to halve gather traffic.
// fp32 state: H, r, ftfb, ts.

typedef short bf16x8 __attribute__((ext_vector_type(8)));
typedef float f32x4 __attribute__((ext_vector_type(4)));
typedef unsigned short u16x8 __attribute__((ext_vector_type(8)));

__device__ __forceinline__ float bf2f(unsigned short u) {
  return __uint_as_float(((unsigned)u) << 16);
}
__device__ __forceinline__ unsigned short f2bf(float f) {
  unsigned u = __float_as_uint(f);
  unsigned r = (u + 0x7FFFu + ((u >> 16) & 1u)) >> 16;
  return (unsigned short)r;
}
__device__ __forceinline__ float softplusf(float x) {
  return x > 20.f ? x : log1pf(expf(x));
}

// ---------------- setup kernels ----------------

__global__ void count_kernel(const int* __restrict__ col, int E, int* __restrict__ cnt) {
  int e = blockIdx.x * blockDim.x + threadIdx.x;
  if (e < E) atomicAdd(&cnt[col[e]], 1);
}

__global__ __launch_bounds__(1024) void scan_kernel(int* cnt, int* colptr, float* dinv, int N) {
  __shared__ int sums[1024];
  int tid = threadIdx.x;
  int chunk = (N + 1023) >> 10;
  int start = tid * chunk;
  int end = min(start + chunk, N);
  int s = 0;
  for (int i = start; i < end; i++) s += cnt[i];
  sums[tid] = s;
  __syncthreads();
  for (int off = 1; off < 1024; off <<= 1) {
    int v = (tid >= off) ? sums[tid - off] : 0;
    __syncthreads();
    sums[tid] += v;
    __syncthreads();
  }
  int incl = sums[tid];
  int run = incl - s;  // exclusive prefix
  for (int i = start; i < end; i++) {
    int c = cnt[i];
    colptr[i] = run;
    run += c;
    dinv[i] = rsqrtf((float)(c + 1));  // self-loop => deg = cnt+1 >= 1
    cnt[i] = 0;                        // reset for cursor reuse
  }
  if (tid == 1023) colptr[N] = incl;
}

__global__ void fill_kernel(const int* __restrict__ row, const int* __restrict__ col, int E,
                            const int* __restrict__ colptr, int* __restrict__ cur,
                            int* __restrict__ csr) {
  int e = blockIdx.x * blockDim.x + threadIdx.x;
  if (e < E) {
    int c = col[e];
    int pos = colptr[c] + atomicAdd(&cur[c], 1);
    csr[pos] = row[e];
  }
}

// Transposed bf16 weights:
// WnodeT (384 x 64): row j = output col of [Omega_as | W_s | fc1_top | fc1_bot], col k = H dim
// WencT  (64 x 128): WencT[j][k] = Wenc[k][j]
// Wp1T   (64 x 128): Wp1T[j][k] = Wp1[k][j]
__global__ void prep_weights(const float* __restrict__ Om, const float* __restrict__ Wsr,
                             const float* __restrict__ Wfc1, const float* __restrict__ Wenc,
                             const float* __restrict__ Wp1, unsigned short* __restrict__ WnodeT,
                             unsigned short* __restrict__ WencT, unsigned short* __restrict__ Wp1T) {
  int idx = blockIdx.x * blockDim.x + threadIdx.x;
  if (idx < 384 * 64) {
    int j = idx / 64, k = idx % 64;
    float v;
    if (j < 64) {
      v = Om[k * 64 + j] - Om[j * 64 + k];
    } else if (j < 128) {
      int jj = j - 64;
      v = 0.5f * (Wsr[k * 64 + jj] + Wsr[jj * 64 + k]);
    } else if (j < 256) {
      v = Wfc1[k * 128 + (j - 128)];
    } else {
      v = Wfc1[(64 + k) * 128 + (j - 256)];
    }
    WnodeT[idx] = f2bf(v);
  } else if (idx < 384 * 64 + 64 * 128) {
    int t = idx - 384 * 64;
    int j = t / 128, k = t % 128;
    WencT[t] = f2bf(Wenc[k * 64 + j]);
  } else if (idx < 384 * 64 + 2 * 64 * 128) {
    int t = idx - 384 * 64 - 64 * 128;
    int j = t / 128, k = t % 128;
    Wp1T[t] = f2bf(Wp1[k * 64 + j]);
  }
}

__global__ void cvt_bf16_kernel(const float* __restrict__ in, unsigned short* __restrict__ out,
                                int n4) {
  int i = blockIdx.x * blockDim.x + threadIdx.x;
  if (i >= n4) return;
  float4 v = ((const float4*)in)[i];
  ushort4 o;
  o.x = f2bf(v.x);
  o.y = f2bf(v.y);
  o.z = f2bf(v.z);
  o.w = f2bf(v.w);
  ((ushort4*)out)[i] = o;
}

// ---------------- encoder GEMM: H = relu(x @ Wenc), K=128, 64 cols ----------------
// wave = 16 rows; writes H (f32) and Hbf (bf16)

__global__ __launch_bounds__(256, 4) void enc_gemm(const unsigned short* __restrict__ Xb,
                                                   const unsigned short* __restrict__ WT,
                                                   float* __restrict__ H,
                                                   unsigned short* __restrict__ Hbf, int N) {
  int gw = blockIdx.x * 4 + (threadIdx.x >> 6);
  int l = threadIdx.x & 63;
  int r0 = gw * 16;
  if (r0 >= N) return;
  int arow = min(r0 + (l & 15), N - 1);
  int ak = (l >> 4) * 8;
  bf16x8 a[4];
#pragma unroll
  for (int kk = 0; kk < 4; kk++)
    a[kk] = *(const bf16x8*)(Xb + (size_t)arow * 128 + kk * 32 + ak);
  int rbase = r0 + (l >> 4) * 4;
#pragma unroll
  for (int c = 0; c < 4; c++) {
    const unsigned short* wp = WT + (size_t)(c * 16 + (l & 15)) * 128 + ak;
    f32x4 acc = {0.f, 0.f, 0.f, 0.f};
#pragma unroll
    for (int kk = 0; kk < 4; kk++)
      acc = __builtin_amdgcn_mfma_f32_16x16x32_bf16(a[kk], *(const bf16x8*)(wp + kk * 32), acc,
                                                    0, 0, 0);
    int gcol = c * 16 + (l & 15);
#pragma unroll
    for (int b = 0; b < 4; b++) {
      int gr = rbase + b;
      if (gr < N) {
        float v = fmaxf(acc[b], 0.f);
        H[(size_t)gr * 64 + gcol] = v;
        Hbf[(size_t)gr * 64 + gcol] = f2bf(v);
      }
    }
  }
}

// ---------------- node GEMM: NodeBufB = Hb @ Wnode (K=64, 384 cols, bf16 out) ----------------
// cols [64,128) scaled by dinv[row] in epilogue

__global__ __launch_bounds__(256, 4) void node_gemm(const unsigned short* __restrict__ Hb,
                                                    const unsigned short* __restrict__ WT,
                                                    unsigned short* __restrict__ NodeBufB,
                                                    const float* __restrict__ dinv, int N) {
  int gw = blockIdx.x * 4 + (threadIdx.x >> 6);
  int l = threadIdx.x & 63;
  int r0 = gw * 16;
  if (r0 >= N) return;
  int arow = min(r0 + (l & 15), N - 1);
  int ak = (l >> 4) * 8;
  bf16x8 a0 = *(const bf16x8*)(Hb + (size_t)arow * 64 + ak);
  bf16x8 a1 = *(const bf16x8*)(Hb + (size_t)arow * 64 + 32 + ak);
  int rbase = r0 + (l >> 4) * 4;
  float dv[4];
#pragma unroll
  for (int b = 0; b < 4; b++) dv[b] = dinv[min(rbase + b, N - 1)];
#pragma unroll
  for (int c = 0; c < 24; c++) {
    const unsigned short* wp = WT + (size_t)(c * 16 + (l & 15)) * 64 + ak;
    bf16x8 b0 = *(const bf16x8*)(wp);
    bf16x8 b1 = *(const bf16x8*)(wp + 32);
    f32x4 acc = {0.f, 0.f, 0.f, 0.f};
    acc = __builtin_amdgcn_mfma_f32_16x16x32_bf16(a0, b0, acc, 0, 0, 0);
    acc = __builtin_amdgcn_mfma_f32_16x16x32_bf16(a1, b1, acc, 0, 0, 0);
    int gcol = c * 16 + (l & 15);
    bool scale = (c >= 4 && c < 8);
#pragma unroll
    for (int b = 0; b < 4; b++) {
      int gr = rbase + b;
      if (gr < N) {
        float v = acc[b];
        if (scale) v *= dv[b];
        NodeBufB[(size_t)gr * 384 + gcol] = f2bf(v);
      }
    }
  }
}

// ---------------- aggregation: wave per node ----------------
// sym = dinv[c]*(sum_in Bs[s] + Bs[c]); dH = relu(tanh(sym - relu(A)));
// H += dH (f32 + bf16 copy); ft/fb = old_H . Wfv halves

__global__ __launch_bounds__(256) void aggregate_kernel(
    const unsigned short* __restrict__ NodeBufB, const float* __restrict__ dinv,
    const int* __restrict__ colptr, const int* __restrict__ csr, const float* __restrict__ Wfv,
    float* __restrict__ H, unsigned short* __restrict__ Hbf, unsigned short* __restrict__ dHb,
    float* __restrict__ ftfb, int N) {
  int c = blockIdx.x * 4 + (threadIdx.x >> 6);
  int j = threadIdx.x & 63;
  if (c >= N) return;
  float acc = bf2f(NodeBufB[(size_t)c * 384 + 64 + j]);  // self-loop (already dinv[src]-scaled)
  int beg = colptr[c], end = colptr[c + 1];
  for (int i = beg; i < end; i++) {
    int s = csr[i];
    acc += bf2f(NodeBufB[(size_t)s * 384 + 64 + j]);
  }
  float sym = dinv[c] * acc;
  float a = bf2f(NodeBufB[(size_t)c * 384 + j]);
  float dh = tanhf(sym - fmaxf(a, 0.f));
  dh = fmaxf(dh, 0.f);
  dHb[(size_t)c * 64 + j] = f2bf(dh);
  float h = H[(size_t)c * 64 + j];
  float hn = h + dh;
  H[(size_t)c * 64 + j] = hn;
  Hbf[(size_t)c * 64 + j] = f2bf(hn);
  float p0 = h * Wfv[j];
  float p1 = h * Wfv[64 + j];
#pragma unroll
  for (int off = 32; off >= 1; off >>= 1) {
    p0 += __shfl_xor(p0, off, 64);
    p1 += __shfl_xor(p1, off, 64);
  }
  if (j == 0) {
    ftfb[2 * c] = p0;
    ftfb[2 * c + 1] = p1;
  }
}

// ---------------- r init: r = concat(H0[src], H0[dst]) ----------------

__global__ void rinit_kernel(const float* __restrict__ H, const int* __restrict__ pairs,
                             float* __restrict__ r, int P) {
  int idx = blockIdx.x * blockDim.x + threadIdx.x;
  int p = idx >> 5;
  if (p >= P) return;
  int q = idx & 31;
  int j = q * 4;
  int node = (j < 64) ? pairs[2 * p] : pairs[2 * p + 1];
  int jj = j & 63;
  float4 v = *(const float4*)(H + (size_t)node * 64 + jj);
  *(float4*)(r + (size_t)p * 128 + j) = v;
}

// ---------------- pair kernel: 16 lanes per pair, bf16 gathers ----------------

__global__ __launch_bounds__(256) void pair_kernel(
    const unsigned short* __restrict__ NodeBufB, const float* __restrict__ ftfb,
    const unsigned short* __restrict__ dHb, const int* __restrict__ pairs,
    const float* __restrict__ gum, const float* __restrict__ Wfc2, float* __restrict__ r,
    float* __restrict__ ts, int P, int first) {
  int p = blockIdx.x * 16 + (threadIdx.x >> 4);
  int l = threadIdx.x & 15;
  if (p >= P) return;
  int src = pairs[2 * p], dst = pairs[2 * p + 1];
  u16x8 tv = *(const u16x8*)(NodeBufB + (size_t)src * 384 + 128 + l * 8);
  u16x8 dv = *(const u16x8*)(NodeBufB + (size_t)dst * 384 + 256 + l * 8);
  float l0 = 0.f, l1 = 0.f;
#pragma unroll
  for (int i = 0; i < 8; i++) {
    float zz = fmaxf(bf2f(tv[i]) + bf2f(dv[i]), 0.f);
    int m = l * 8 + i;
    l0 = fmaf(zz, Wfc2[2 * m], l0);
    l1 = fmaf(zz, Wfc2[2 * m + 1], l1);
  }
#pragma unroll
  for (int off = 1; off < 16; off <<= 1) {
    l0 += __shfl_xor(l0, off, 64);
    l1 += __shfl_xor(l1, off, 64);
  }
  float nu = softplusf(ftfb[2 * src] + ftfb[2 * dst + 1]) + 1.0f;
  float g0 = gum[2 * (size_t)p], g1 = gum[2 * (size_t)p + 1];
  float dlt = ((l1 + g1) - (l0 + g0)) / nu;
  float tau = 1.0f / (1.0f + expf(dlt));

  const unsigned short* drp =
      (l < 8) ? (dHb + (size_t)src * 64 + l * 8) : (dHb + (size_t)dst * 64 + (l - 8) * 8);
  u16x8 av = *(const u16x8*)drp;
  float* rp = r + (size_t)p * 128 + l * 8;
  float4 r0 = *(float4*)rp;
  float4 r1 = *(float4*)(rp + 4);
  r0.x = fmaf(tau, bf2f(av[0]), r0.x);
  r0.y = fmaf(tau, bf2f(av[1]), r0.y);
  r0.z = fmaf(tau, bf2f(av[2]), r0.z);
  r0.w = fmaf(tau, bf2f(av[3]), r0.w);
  r1.x = fmaf(tau, bf2f(av[4]), r1.x);
  r1.y = fmaf(tau, bf2f(av[5]), r1.y);
  r1.z = fmaf(tau, bf2f(av[6]), r1.z);
  r1.w = fmaf(tau, bf2f(av[7]), r1.w);
  *(float4*)rp = r0;
  *(float4*)(rp + 4) = r1;
  if (l == 0) {
    if (first) ts[p] = tau;
    else ts[p] += tau;
  }
}

// ---------------- final: scores = (relu(rb @ Wp1) @ Wp2), fused ----------------

__global__ __launch_bounds__(256, 4) void final_gemm(const unsigned short* __restrict__ rb,
                                                     const unsigned short* __restrict__ WT,
                                                     const float* __restrict__ Wp2,
                                                     float* __restrict__ out, int P) {
  int gw = blockIdx.x * 4 + (threadIdx.x >> 6);
  int l = threadIdx.x & 63;
  int r0 = gw * 16;
  if (r0 >= P) return;
  int arow = min(r0 + (l & 15), P - 1);
  int ak = (l >> 4) * 8;
  bf16x8 a[4];
#pragma unroll
  for (int kk = 0; kk < 4; kk++)
    a[kk] = *(const bf16x8*)(rb + (size_t)arow * 128 + kk * 32 + ak);
  float s[4] = {0.f, 0.f, 0.f, 0.f};
#pragma unroll
  for (int c = 0; c < 4; c++) {
    const unsigned short* wp = WT + (size_t)(c * 16 + (l & 15)) * 128 + ak;
    f32x4 acc = {0.f, 0.f, 0.f, 0.f};
#pragma unroll
    for (int kk = 0; kk < 4; kk++)
      acc = __builtin_amdgcn_mfma_f32_16x16x32_bf16(a[kk], *(const bf16x8*)(wp + kk * 32), acc,
                                                    0, 0, 0);
    float w = Wp2[c * 16 + (l & 15)];
#pragma unroll
    for (int b = 0; b < 4; b++) s[b] = fmaf(fmaxf(acc[b], 0.f), w, s[b]);
  }
#pragma unroll
  for (int off = 1; off < 16; off <<= 1) {
#pragma unroll
    for (int b = 0; b < 4; b++) s[b] += __shfl_xor(s[b], off, 64);
  }
  if ((l & 15) == 0) {
    int rbase = r0 + (l >> 4) * 4;
#pragma unroll
    for (int b = 0; b < 4; b++) {
      int gr = rbase + b;
      if (gr < P) out[gr] = s[b];
    }
  }
}

// ---------------- launch ----------------

extern "C" void kernel_launch(void* const* d_in, const int* in_sizes, int n_in, void* d_out,
                              int out_size, void* d_ws, size_t ws_size, hipStream_t stream) {
  const float* x = (const float*)d_in[0];
  const int* edge = (const int*)d_in[1];
  const int* pairs = (const int*)d_in[2];
  const float* gumbel = (const float*)d_in[3];
  const float* Wenc = (const float*)d_in[4];
  const float* Om = (const float*)d_in[5];
  const float* Wsr = (const float*)d_in[6];
  const float* Wfc1 = (const float*)d_in[7];
  const float* Wfc2 = (const float*)d_in[8];
  const float* Wfv = (const float*)d_in[9];
  const float* Wp1 = (const float*)d_in[10];
  const float* Wp2 = (const float*)d_in[11];
  const int IN = 128;
  const int N = in_sizes[0] / IN;
  const int E = in_sizes[1] / 2;
  const int P = in_sizes[2] / 2;
  const int L = in_sizes[3] / (2 * P);
  float* out = (float*)d_out;

  char* wsb = (char*)d_ws;
  size_t off = 0;
  auto alloc = [&](size_t bytes) -> char* {
    char* p = wsb + off;
    off = (off + bytes + 255) & ~(size_t)255;
    return p;
  };
  float* dinv = (float*)alloc((size_t)N * 4);
  int* cnt = (int*)alloc((size_t)N * 4);
  int* colptr = (int*)alloc((size_t)(N + 1) * 4);
  int* csr = (int*)alloc((size_t)E * 4);
  unsigned short* WnodeT = (unsigned short*)alloc((size_t)384 * 64 * 2);
  unsigned short* WencT = (unsigned short*)alloc((size_t)64 * 128 * 2);
  unsigned short* Wp1T = (unsigned short*)alloc((size_t)64 * 128 * 2);
  unsigned short* xb = (unsigned short*)alloc((size_t)N * 128 * 2);
  float* H = (float*)alloc((size_t)N * 64 * 4);
  unsigned short* Hbf = (unsigned short*)alloc((size_t)N * 64 * 2);
  unsigned short* dHb = (unsigned short*)alloc((size_t)N * 64 * 2);
  unsigned short* NodeBufB = (unsigned short*)alloc((size_t)N * 384 * 2);
  float* ftfb = (float*)alloc((size_t)N * 2 * 4);
  float* r = (float*)alloc((size_t)P * 128 * 4);
  unsigned short* rb = (unsigned short*)alloc((size_t)P * 128 * 2);
  (void)ws_size;
  (void)n_in;
  (void)out_size;

  const int* erow = edge;
  const int* ecol = edge + E;

  hipMemsetAsync(cnt, 0, (size_t)N * 4, stream);
  count_kernel<<<(E + 255) / 256, 256, 0, stream>>>(ecol, E, cnt);
  scan_kernel<<<1, 1024, 0, stream>>>(cnt, colptr, dinv, N);
  fill_kernel<<<(E + 255) / 256, 256, 0, stream>>>(erow, ecol, E, colptr, cnt, csr);
  prep_weights<<<(384 * 64 + 2 * 64 * 128 + 255) / 256, 256, 0, stream>>>(
      Om, Wsr, Wfc1, Wenc, Wp1, WnodeT, WencT, Wp1T);
  cvt_bf16_kernel<<<((N * 32) + 255) / 256, 256, 0, stream>>>(x, xb, N * 32);

  int nwaves = (N + 15) / 16;
  enc_gemm<<<(nwaves + 3) / 4, 256, 0, stream>>>(xb, WencT, H, Hbf, N);
  rinit_kernel<<<((P * 32) + 255) / 256, 256, 0, stream>>>(H, pairs, r, P);

  for (int t = 0; t < L; t++) {
    node_gemm<<<(nwaves + 3) / 4, 256, 0, stream>>>(Hbf, WnodeT, NodeBufB, dinv, N);
    aggregate_kernel<<<(N + 3) / 4, 256, 0, stream>>>(NodeBufB, dinv, colptr, csr, Wfv, H, Hbf,
                                                      dHb, ftfb, N);
    pair_kernel<<<(P + 15) / 16, 256, 0, stream>>>(NodeBufB, ftfb, dHb, pairs,
                                                   gumbel + (size_t)t * P * 2, Wfc2, r, out + P,
                                                   P, t == 0);
  }
  cvt_bf16_kernel<<<((P * 32) + 255) / 256, 256, 0, stream>>>(r, rb, P * 32);
  int pwaves = (P + 15) / 16;
  final_gemm<<<(pwaves + 3) / 4, 256, 0, stream>>>(rb, Wp1T, Wp2, out, P);
}

// Round 3
// 1065.559 us; speedup vs baseline: 2.5491x; 1.4462x over previous
//
#include <hip/hip_runtime.h>
#include <math.h>

// EELP: 20-step GNN scan, MFMA-bf16, deferred-r edition.
// Step loop computes only tau[t][p] (plus dH_t, stored); r is rebuilt once at
// the end: r = [H0[src],H0[dst]] + sum_t tau_t * [dH_t[src],dH_t[dst]].
// node_gemm stages its 48KB weight panel in LDS (72-short padded rows).

typedef short bf16x8 __attribute__((ext_vector_type(8)));
typedef float f32x4 __attribute__((ext_vector_type(4)));
typedef unsigned short u16x8 __attribute__((ext_vector_type(8)));

__device__ __forceinline__ float bf2f(unsigned short u) {
  return __uint_as_float(((unsigned)u) << 16);
}
__device__ __forceinline__ unsigned short f2bf(float f) {
  unsigned u = __float_as_uint(f);
  unsigned r = (u + 0x7FFFu + ((u >> 16) & 1u)) >> 16;
  return (unsigned short)r;
}
__device__ __forceinline__ float softplusf(float x) {
  return x > 20.f ? x : log1pf(expf(x));
}

// ---------------- setup: degree count + 3-phase scan + CSR fill ----------------

__global__ void count_kernel(const int* __restrict__ col, int E, int* __restrict__ cnt) {
  int e = blockIdx.x * blockDim.x + threadIdx.x;
  if (e < E) atomicAdd(&cnt[col[e]], 1);
}

__global__ __launch_bounds__(1024) void scan1_kernel(int* __restrict__ cnt,
                                                     int* __restrict__ colptr,
                                                     float* __restrict__ dinv,
                                                     int* __restrict__ bsum, int N) {
  __shared__ int sh[1024];
  int t = threadIdx.x, b = blockIdx.x;
  int i = b * 1024 + t;
  int v = (i < N) ? cnt[i] : 0;
  sh[t] = v;
  __syncthreads();
  for (int off = 1; off < 1024; off <<= 1) {
    int o = (t >= off) ? sh[t - off] : 0;
    __syncthreads();
    sh[t] += o;
    __syncthreads();
  }
  if (i < N) {
    colptr[i] = sh[t] - v;  // exclusive (within block)
    dinv[i] = rsqrtf((float)(v + 1));
    cnt[i] = 0;  // reset cursor for fill
  }
  if (t == 1023) bsum[b] = sh[1023];
}

__global__ void scan2_kernel(int* __restrict__ bsum, int B) {
  if (threadIdx.x == 0 && blockIdx.x == 0) {
    int run = 0;
    for (int b = 0; b < B; b++) {
      int x = bsum[b];
      bsum[b] = run;
      run += x;
    }
    bsum[B] = run;
  }
}

__global__ void scan3_kernel(int* __restrict__ colptr, const int* __restrict__ bsum, int N) {
  int i = blockIdx.x * blockDim.x + threadIdx.x;
  if (i < N) colptr[i] += bsum[i >> 10];
  if (i == N) colptr[N] = bsum[(N + 1023) >> 10];
}

__global__ void fill_kernel(const int* __restrict__ row, const int* __restrict__ col, int E,
                            const int* __restrict__ colptr, int* __restrict__ cur,
                            int* __restrict__ csr) {
  int e = blockIdx.x * blockDim.x + threadIdx.x;
  if (e < E) {
    int c = col[e];
    int pos = colptr[c] + atomicAdd(&cur[c], 1);
    csr[pos] = row[e];
  }
}

// Transposed bf16 weights (row j = output col, col k = input dim):
// WnodeT (384 x 64): [Omega_as | W_s | fc1_top | fc1_bot]
// WencT  (64 x 128), Wp1T (64 x 128)
__global__ void prep_weights(const float* __restrict__ Om, const float* __restrict__ Wsr,
                             const float* __restrict__ Wfc1, const float* __restrict__ Wenc,
                             const float* __restrict__ Wp1, unsigned short* __restrict__ WnodeT,
                             unsigned short* __restrict__ WencT, unsigned short* __restrict__ Wp1T) {
  int idx = blockIdx.x * blockDim.x + threadIdx.x;
  if (idx < 384 * 64) {
    int j = idx / 64, k = idx % 64;
    float v;
    if (j < 64) {
      v = Om[k * 64 + j] - Om[j * 64 + k];
    } else if (j < 128) {
      int jj = j - 64;
      v = 0.5f * (Wsr[k * 64 + jj] + Wsr[jj * 64 + k]);
    } else if (j < 256) {
      v = Wfc1[k * 128 + (j - 128)];
    } else {
      v = Wfc1[(64 + k) * 128 + (j - 256)];
    }
    WnodeT[idx] = f2bf(v);
  } else if (idx < 384 * 64 + 64 * 128) {
    int t = idx - 384 * 64;
    int j = t / 128, k = t % 128;
    WencT[t] = f2bf(Wenc[k * 64 + j]);
  } else if (idx < 384 * 64 + 2 * 64 * 128) {
    int t = idx - 384 * 64 - 64 * 128;
    int j = t / 128, k = t % 128;
    Wp1T[t] = f2bf(Wp1[k * 64 + j]);
  }
}

// ---------------- encoder GEMM: H = relu(x @ Wenc), K=128 ----------------
// reads f32 x directly (converts in-kernel); writes H (f32), H0 (f32 copy), Hbf (bf16)

__global__ __launch_bounds__(256, 4) void enc_gemm(const float* __restrict__ X,
                                                   const unsigned short* __restrict__ WT,
                                                   float* __restrict__ H, float* __restrict__ H0,
                                                   unsigned short* __restrict__ Hbf, int N) {
  int gw = blockIdx.x * 4 + (threadIdx.x >> 6);
  int l = threadIdx.x & 63;
  int r0 = gw * 16;
  if (r0 >= N) return;
  int arow = min(r0 + (l & 15), N - 1);
  int ak = (l >> 4) * 8;
  bf16x8 a[4];
#pragma unroll
  for (int kk = 0; kk < 4; kk++) {
    const float* xp = X + (size_t)arow * 128 + kk * 32 + ak;
    float4 u = *(const float4*)xp;
    float4 v = *(const float4*)(xp + 4);
    bf16x8 t;
    t[0] = (short)f2bf(u.x); t[1] = (short)f2bf(u.y);
    t[2] = (short)f2bf(u.z); t[3] = (short)f2bf(u.w);
    t[4] = (short)f2bf(v.x); t[5] = (short)f2bf(v.y);
    t[6] = (short)f2bf(v.z); t[7] = (short)f2bf(v.w);
    a[kk] = t;
  }
  int rbase = r0 + (l >> 4) * 4;
#pragma unroll
  for (int c = 0; c < 4; c++) {
    const unsigned short* wp = WT + (size_t)(c * 16 + (l & 15)) * 128 + ak;
    f32x4 acc = {0.f, 0.f, 0.f, 0.f};
#pragma unroll
    for (int kk = 0; kk < 4; kk++)
      acc = __builtin_amdgcn_mfma_f32_16x16x32_bf16(a[kk], *(const bf16x8*)(wp + kk * 32), acc,
                                                    0, 0, 0);
    int gcol = c * 16 + (l & 15);
#pragma unroll
    for (int b = 0; b < 4; b++) {
      int gr = rbase + b;
      if (gr < N) {
        float v = fmaxf(acc[b], 0.f);
        H[(size_t)gr * 64 + gcol] = v;
        H0[(size_t)gr * 64 + gcol] = v;
        Hbf[(size_t)gr * 64 + gcol] = f2bf(v);
      }
    }
  }
}

// ---------------- node GEMM: NodeBufB = Hb @ Wnode (K=64, 384 cols, bf16 out) ----------------
// weight panel staged in LDS, rows padded to 72 shorts (2-way bank aliasing = free)

__global__ __launch_bounds__(256) void node_gemm(const unsigned short* __restrict__ Hb,
                                                 const unsigned short* __restrict__ WT,
                                                 unsigned short* __restrict__ NodeBufB,
                                                 const float* __restrict__ dinv, int N) {
  __shared__ unsigned short sw[384 * 72];
  int tid = threadIdx.x;
  for (int idx = tid; idx < 384 * 8; idx += 256) {
    int row = idx >> 3, seg = idx & 7;
    *(u16x8*)(sw + row * 72 + seg * 8) = *(const u16x8*)(WT + row * 64 + seg * 8);
  }
  __syncthreads();
  int gw = blockIdx.x * 4 + (tid >> 6);
  int l = tid & 63;
  int r0 = gw * 16;
  if (r0 >= N) return;
  int arow = min(r0 + (l & 15), N - 1);
  int ak = (l >> 4) * 8;
  bf16x8 a0 = *(const bf16x8*)(Hb + (size_t)arow * 64 + ak);
  bf16x8 a1 = *(const bf16x8*)(Hb + (size_t)arow * 64 + 32 + ak);
  int rbase = r0 + (l >> 4) * 4;
  float dv[4];
#pragma unroll
  for (int b = 0; b < 4; b++) dv[b] = dinv[min(rbase + b, N - 1)];
#pragma unroll
  for (int c = 0; c < 24; c++) {
    const unsigned short* wp = sw + (c * 16 + (l & 15)) * 72 + ak;
    bf16x8 b0 = *(const bf16x8*)(wp);
    bf16x8 b1 = *(const bf16x8*)(wp + 32);
    f32x4 acc = {0.f, 0.f, 0.f, 0.f};
    acc = __builtin_amdgcn_mfma_f32_16x16x32_bf16(a0, b0, acc, 0, 0, 0);
    acc = __builtin_amdgcn_mfma_f32_16x16x32_bf16(a1, b1, acc, 0, 0, 0);
    int gcol = c * 16 + (l & 15);
    bool scale = (c >= 4 && c < 8);
#pragma unroll
    for (int b = 0; b < 4; b++) {
      int gr = rbase + b;
      if (gr < N) {
        float v = acc[b];
        if (scale) v *= dv[b];
        NodeBufB[(size_t)gr * 384 + gcol] = f2bf(v);
      }
    }
  }
}

// ---------------- aggregation: wave per node, 4 neighbors/iter ----------------
// lane group g=l>>4 handles neighbors beg+g, beg+g+4, ...; each lane 4 dims (q..q+3).
// sym = dinv[c]*(sum_in Bs[s] + Bs[c]); dh = relu(tanh(sym - relu(A)));
// group0 writes dH_t (bf16); group1 updates H/Hbf and reduces ftfb from pre-update H.

__global__ __launch_bounds__(256) void aggregate_kernel(
    const unsigned short* __restrict__ NodeBufB, const float* __restrict__ dinv,
    const int* __restrict__ colptr, const int* __restrict__ csr, const float* __restrict__ Wfv,
    float* __restrict__ H, unsigned short* __restrict__ Hbf, unsigned short* __restrict__ dHt,
    float* __restrict__ ftfb, int N) {
  int c = blockIdx.x * 4 + (threadIdx.x >> 6);
  if (c >= N) return;
  int l = threadIdx.x & 63;
  int g = l >> 4;
  int q = (l & 15) * 4;
  const unsigned short* Bs = NodeBufB + 64;
  float acc[4] = {0.f, 0.f, 0.f, 0.f};
  if (g == 0) {
    ushort4 v = *(const ushort4*)(Bs + (size_t)c * 384 + q);
    acc[0] = bf2f(v.x); acc[1] = bf2f(v.y); acc[2] = bf2f(v.z); acc[3] = bf2f(v.w);
  }
  int beg = colptr[c], end = colptr[c + 1];
  int i = beg + g;
  for (; i + 4 < end; i += 8) {
    int s0 = csr[i], s1 = csr[i + 4];
    ushort4 v0 = *(const ushort4*)(Bs + (size_t)s0 * 384 + q);
    ushort4 v1 = *(const ushort4*)(Bs + (size_t)s1 * 384 + q);
    acc[0] += bf2f(v0.x) + bf2f(v1.x);
    acc[1] += bf2f(v0.y) + bf2f(v1.y);
    acc[2] += bf2f(v0.z) + bf2f(v1.z);
    acc[3] += bf2f(v0.w) + bf2f(v1.w);
  }
  if (i < end) {
    int s0 = csr[i];
    ushort4 v0 = *(const ushort4*)(Bs + (size_t)s0 * 384 + q);
    acc[0] += bf2f(v0.x);
    acc[1] += bf2f(v0.y);
    acc[2] += bf2f(v0.z);
    acc[3] += bf2f(v0.w);
  }
#pragma unroll
  for (int k = 0; k < 4; k++) {
    acc[k] += __shfl_xor(acc[k], 16, 64);
    acc[k] += __shfl_xor(acc[k], 32, 64);
  }
  if (g >= 2) return;
  float dval = dinv[c];
  ushort4 av = *(const ushort4*)(NodeBufB + (size_t)c * 384 + q);
  float dh[4];
  dh[0] = fmaxf(tanhf(dval * acc[0] - fmaxf(bf2f(av.x), 0.f)), 0.f);
  dh[1] = fmaxf(tanhf(dval * acc[1] - fmaxf(bf2f(av.y), 0.f)), 0.f);
  dh[2] = fmaxf(tanhf(dval * acc[2] - fmaxf(bf2f(av.z), 0.f)), 0.f);
  dh[3] = fmaxf(tanhf(dval * acc[3] - fmaxf(bf2f(av.w), 0.f)), 0.f);
  if (g == 0) {
    ushort4 o;
    o.x = f2bf(dh[0]); o.y = f2bf(dh[1]); o.z = f2bf(dh[2]); o.w = f2bf(dh[3]);
    *(ushort4*)(dHt + (size_t)c * 64 + q) = o;
  } else {
    float* hp = H + (size_t)c * 64 + q;
    float4 h = *(const float4*)hp;
    float4 hn;
    hn.x = h.x + dh[0]; hn.y = h.y + dh[1]; hn.z = h.z + dh[2]; hn.w = h.w + dh[3];
    *(float4*)hp = hn;
    ushort4 ob;
    ob.x = f2bf(hn.x); ob.y = f2bf(hn.y); ob.z = f2bf(hn.z); ob.w = f2bf(hn.w);
    *(ushort4*)(Hbf + (size_t)c * 64 + q) = ob;
    // ftfb from pre-update h
    float p0 = h.x * Wfv[q] + h.y * Wfv[q + 1] + h.z * Wfv[q + 2] + h.w * Wfv[q + 3];
    float p1 = h.x * Wfv[64 + q] + h.y * Wfv[64 + q + 1] + h.z * Wfv[64 + q + 2] +
               h.w * Wfv[64 + q + 3];
#pragma unroll
    for (int off = 1; off < 16; off <<= 1) {
      p0 += __shfl_xor(p0, off, 64);
      p1 += __shfl_xor(p1, off, 64);
    }
    if ((l & 15) == 0) {
      ftfb[2 * c] = p0;
      ftfb[2 * c + 1] = p1;
    }
  }
}

// ---------------- pair tau: 16 lanes per pair, writes tau[t*P+p] only ----------------

__global__ __launch_bounds__(256) void pair_tau_kernel(
    const unsigned short* __restrict__ NodeBufB, const float* __restrict__ ftfb,
    const int* __restrict__ pairs, const float* __restrict__ gum,
    const float* __restrict__ Wfc2, float* __restrict__ tau_out, int P) {
  int p = blockIdx.x * 16 + (threadIdx.x >> 4);
  int l = threadIdx.x & 15;
  if (p >= P) return;
  int src = pairs[2 * p], dst = pairs[2 * p + 1];
  u16x8 tv = *(const u16x8*)(NodeBufB + (size_t)src * 384 + 128 + l * 8);
  u16x8 dv = *(const u16x8*)(NodeBufB + (size_t)dst * 384 + 256 + l * 8);
  float l0 = 0.f, l1 = 0.f;
#pragma unroll
  for (int i = 0; i < 8; i++) {
    float zz = fmaxf(bf2f(tv[i]) + bf2f(dv[i]), 0.f);
    int m = l * 8 + i;
    l0 = fmaf(zz, Wfc2[2 * m], l0);
    l1 = fmaf(zz, Wfc2[2 * m + 1], l1);
  }
#pragma unroll
  for (int off = 1; off < 16; off <<= 1) {
    l0 += __shfl_xor(l0, off, 64);
    l1 += __shfl_xor(l1, off, 64);
  }
  if (l == 0) {
    float nu = softplusf(ftfb[2 * src] + ftfb[2 * dst + 1]) + 1.0f;
    float g0 = gum[2 * (size_t)p], g1 = gum[2 * (size_t)p + 1];
    float dlt = ((l1 + g1) - (l0 + g0)) / nu;
    tau_out[p] = 1.0f / (1.0f + expf(dlt));
  }
}

// ---------------- r build (deferred): rb = bf16(H0 pair + sum_t tau*dH_t); ts = sum tau ----

__global__ __launch_bounds__(256) void rbuild_kernel(
    const float* __restrict__ H0, const unsigned short* __restrict__ dHall,
    const float* __restrict__ tau, const int* __restrict__ pairs,
    unsigned short* __restrict__ rb, float* __restrict__ ts, int P, int N, int Lsteps) {
  int p = blockIdx.x * 16 + (threadIdx.x >> 4);
  int l = threadIdx.x & 15;
  if (p >= P) return;
  int node = (l < 8) ? pairs[2 * p] : pairs[2 * p + 1];
  int d0 = (l & 7) * 8;
  const float* hp = H0 + (size_t)node * 64 + d0;
  float4 h0 = *(const float4*)hp;
  float4 h1 = *(const float4*)(hp + 4);
  float acc[8] = {h0.x, h0.y, h0.z, h0.w, h1.x, h1.y, h1.z, h1.w};
  float tsum = 0.f;
  const unsigned short* dbase = dHall + (size_t)node * 64 + d0;
#pragma unroll 2
  for (int t = 0; t < Lsteps; t++) {
    float tt = tau[(size_t)t * P + p];
    tsum += tt;
    u16x8 v = *(const u16x8*)(dbase + (size_t)t * N * 64);
#pragma unroll
    for (int i = 0; i < 8; i++) acc[i] = fmaf(tt, bf2f(v[i]), acc[i]);
  }
  u16x8 o;
#pragma unroll
  for (int i = 0; i < 8; i++) o[i] = f2bf(acc[i]);
  *(u16x8*)(rb + (size_t)p * 128 + l * 8) = o;
  if (l == 0) ts[p] = tsum;
}

// ---------------- final: scores = (relu(rb @ Wp1) @ Wp2), fused ----------------

__global__ __launch_bounds__(256, 4) void final_gemm(const unsigned short* __restrict__ rb,
                                                     const unsigned short* __restrict__ WT,
                                                     const float* __restrict__ Wp2,
                                                     float* __restrict__ out, int P) {
  int gw = blockIdx.x * 4 + (threadIdx.x >> 6);
  int l = threadIdx.x & 63;
  int r0 = gw * 16;
  if (r0 >= P) return;
  int arow = min(r0 + (l & 15), P - 1);
  int ak = (l >> 4) * 8;
  bf16x8 a[4];
#pragma unroll
  for (int kk = 0; kk < 4; kk++)
    a[kk] = *(const bf16x8*)(rb + (size_t)arow * 128 + kk * 32 + ak);
  float s[4] = {0.f, 0.f, 0.f, 0.f};
#pragma unroll
  for (int c = 0; c < 4; c++) {
    const unsigned short* wp = WT + (size_t)(c * 16 + (l & 15)) * 128 + ak;
    f32x4 acc = {0.f, 0.f, 0.f, 0.f};
#pragma unroll
    for (int kk = 0; kk < 4; kk++)
      acc = __builtin_amdgcn_mfma_f32_16x16x32_bf16(a[kk], *(const bf16x8*)(wp + kk * 32), acc,
                                                    0, 0, 0);
    float w = Wp2[c * 16 + (l & 15)];
#pragma unroll
    for (int b = 0; b < 4; b++) s[b] = fmaf(fmaxf(acc[b], 0.f), w, s[b]);
  }
#pragma unroll
  for (int off = 1; off < 16; off <<= 1) {
#pragma unroll
    for (int b = 0; b < 4; b++) s[b] += __shfl_xor(s[b], off, 64);
  }
  if ((l & 15) == 0) {
    int rbase = r0 + (l >> 4) * 4;
#pragma unroll
    for (int b = 0; b < 4; b++) {
      int gr = rbase + b;
      if (gr < P) out[gr] = s[b];
    }
  }
}

// ---------------- launch ----------------

extern "C" void kernel_launch(void* const* d_in, const int* in_sizes, int n_in, void* d_out,
                              int out_size, void* d_ws, size_t ws_size, hipStream_t stream) {
  const float* x = (const float*)d_in[0];
  const int* edge = (const int*)d_in[1];
  const int* pairs = (const int*)d_in[2];
  const float* gumbel = (const float*)d_in[3];
  const float* Wenc = (const float*)d_in[4];
  const float* Om = (const float*)d_in[5];
  const float* Wsr = (const float*)d_in[6];
  const float* Wfc1 = (const float*)d_in[7];
  const float* Wfc2 = (const float*)d_in[8];
  const float* Wfv = (const float*)d_in[9];
  const float* Wp1 = (const float*)d_in[10];
  const float* Wp2 = (const float*)d_in[11];
  const int IN = 128;
  const int N = in_sizes[0] / IN;
  const int E = in_sizes[1] / 2;
  const int P = in_sizes[2] / 2;
  const int L = in_sizes[3] / (2 * P);
  float* out = (float*)d_out;

  char* wsb = (char*)d_ws;
  size_t off = 0;
  auto alloc = [&](size_t bytes) -> char* {
    char* p = wsb + off;
    off = (off + bytes + 255) & ~(size_t)255;
    return p;
  };
  const int NB = (N + 1023) >> 10;
  float* dinv = (float*)alloc((size_t)N * 4);
  int* cnt = (int*)alloc((size_t)N * 4);
  int* colptr = (int*)alloc((size_t)(N + 1) * 4);
  int* bsum = (int*)alloc((size_t)(NB + 1) * 4);
  int* csr = (int*)alloc((size_t)E * 4);
  unsigned short* WnodeT = (unsigned short*)alloc((size_t)384 * 64 * 2);
  unsigned short* WencT = (unsigned short*)alloc((size_t)64 * 128 * 2);
  unsigned short* Wp1T = (unsigned short*)alloc((size_t)64 * 128 * 2);
  float* H = (float*)alloc((size_t)N * 64 * 4);
  float* H0 = (float*)alloc((size_t)N * 64 * 4);
  unsigned short* Hbf = (unsigned short*)alloc((size_t)N * 64 * 2);
  unsigned short* NodeBufB = (unsigned short*)alloc((size_t)N * 384 * 2);
  float* ftfb = (float*)alloc((size_t)N * 2 * 4);
  unsigned short* dHall = (unsigned short*)alloc((size_t)L * N * 64 * 2);
  float* tau = (float*)alloc((size_t)L * P * 4);
  unsigned short* rb = (unsigned short*)alloc((size_t)P * 128 * 2);
  (void)ws_size;
  (void)n_in;
  (void)out_size;

  const int* erow = edge;
  const int* ecol = edge + E;

  hipMemsetAsync(cnt, 0, (size_t)N * 4, stream);
  count_kernel<<<(E + 255) / 256, 256, 0, stream>>>(ecol, E, cnt);
  scan1_kernel<<<NB, 1024, 0, stream>>>(cnt, colptr, dinv, bsum, N);
  scan2_kernel<<<1, 64, 0, stream>>>(bsum, NB);
  scan3_kernel<<<(N + 256) / 256, 256, 0, stream>>>(colptr, bsum, N);
  fill_kernel<<<(E + 255) / 256, 256, 0, stream>>>(erow, ecol, E, colptr, cnt, csr);
  prep_weights<<<(384 * 64 + 2 * 64 * 128 + 255) / 256, 256, 0, stream>>>(
      Om, Wsr, Wfc1, Wenc, Wp1, WnodeT, WencT, Wp1T);

  int nwaves = (N + 15) / 16;
  enc_gemm<<<(nwaves + 3) / 4, 256, 0, stream>>>(x, WencT, H, H0, Hbf, N);

  for (int t = 0; t < L; t++) {
    node_gemm<<<(nwaves + 3) / 4, 256, 0, stream>>>(Hbf, WnodeT, NodeBufB, dinv, N);
    aggregate_kernel<<<(N + 3) / 4, 256, 0, stream>>>(NodeBufB, dinv, colptr, csr, Wfv, H, Hbf,
                                                      dHall + (size_t)t * N * 64, ftfb, N);
    pair_tau_kernel<<<(P + 15) / 16, 256, 0, stream>>>(NodeBufB, ftfb, pairs,
                                                       gumbel + (size_t)t * P * 2, Wfc2,
                                                       tau + (size_t)t * P, P);
  }
  rbuild_kernel<<<(P + 15) / 16, 256, 0, stream>>>(H0, dHall, tau, pairs, rb, out + P, P, N, L);
  int pwaves = (P + 15) / 16;
  final_gemm<<<(pwaves + 3) / 4, 256, 0, stream>>>(rb, Wp1T, Wp2, out, P);
}